// Round 15
// baseline (395.726 us; speedup 1.0000x reference)
//
#include <hip/hip_runtime.h>
#include <math.h>

typedef float v2 __attribute__((ext_vector_type(2)));

#define SCALE 1073741824.0   // 2^30 fixed-point for deterministic atomic sum
#define NPIX 12582912.0      // 16*3*512*512
#define C1f 1e-4f
#define C2f 9e-4f

#define SEG 288              // floats per LDS slot (imgA 144 | imgB 144)
#define NSLOT 12

struct Wts {
    float w[11];   // V-pass weights
    v2 hp[12];     // H-pass pair weights for element j: (w[j]|0, w[j-1]|0)
};

__device__ __forceinline__ v2 sp(float x) { v2 r; r.x = x; r.y = x; return r; }
__device__ __forceinline__ v2 f2(v2 a, v2 b, v2 c) {
    return __builtin_elementwise_fma(a, b, c);
}

// global load of one staged row (clamped) into named f4 regs
#define GLDP(SM, SE, grow) do {                                             \
    int rc_ = (grow); rc_ = rc_ < 0 ? 0 : (rc_ > 511 ? 511 : rc_);          \
    SM = *(const float4*)(gmain + (size_t)rc_ * 512);                       \
    SE = *(const float4*)(gextra + (size_t)rc_ * 512);                      \
} while (0)

// LDS write of staged row into slot SLW (literal)
#define SWR(SLW, SM, SE) do {                                               \
    *(float4*)(wp1 + (SLW) * SEG) = SM;                                     \
    if (lane < 8) *(float4*)(wp2 + (SLW) * SEG) = SE;                       \
} while (0)

__global__ __launch_bounds__(64, 2) void ssim_main(
    const float* __restrict__ img1, const float* __restrict__ img2,
    unsigned long long* __restrict__ acc, Wts W)
{
    __shared__ float seg[NSLOT * SEG];         // 13824 B, single-wave block

    const int lane = threadIdx.x;              // 64-thread (1-wave) blocks
    const int bx = blockIdx.x;                 // 56 = 14 strips x 4 col groups
    const int strip = bx >> 2, cg = bx & 3;
    const int r0 = strip * 37;                 // 37 output rows per strip
    const int wb = cg * 128;                   // column base
    const int plane = blockIdx.y;              // 48 planes
    const int c = wb + 2 * lane;               // this thread's columns c, c+1

    const float* baseA = img1 + (size_t)plane * 262144;
    const float* baseB = img2 + (size_t)plane * 262144;

    // ---- staging roles: 36 f4 chunks/img cover cols [wb-8, wb+136) ----
    // main: lanes 0-31 -> img A chunks 0-31; lanes 32-63 -> img B chunks 0-31
    // extra: lanes 0-3 -> A chunks 32-35; lanes 4-7 -> B chunks 32-35
    {
    }
    const int mch = lane & 31;
    int mc0 = wb - 8 + 4 * mch;
    mc0 = mc0 < 0 ? 0 : (mc0 > 508 ? 508 : mc0);
    const float* gmain = (lane < 32 ? baseA : baseB) + mc0;
    float* wp1 = seg + (lane < 32 ? 0 : 144) + 4 * mch;

    const int ech = 32 + (lane & 3);
    int ec0 = wb - 8 + 4 * ech;
    ec0 = ec0 < 0 ? 0 : (ec0 > 508 ? 508 : ec0);
    const float* gextra = ((lane & 7) < 4 ? baseA : baseB) + ec0;
    float* wp2 = seg + ((lane & 7) < 4 ? 0 : 144) + 4 * ech;

    // window read base: col c-6 = LDS float (c - wb + 8) - 6 - ... = 2*lane+2
    const float* rdp = seg + 2 * lane + 2;

    // per-lane H weight pairs, zeroed where the element column is out of image
    v2 hpl[12];
#pragma unroll
    for (int j = 0; j < 12; ++j) {
        const int col = c - 5 + j;
        hpl[j] = (col >= 0 && col < 512) ? W.hp[j] : sp(0.f);
    }

    v2 rS[12], rD[12], rP[12], rM[12];         // 12-slot register ring
#pragma unroll
    for (int q = 0; q < 12; ++q) {
        rS[q] = sp(0.f); rD[q] = sp(0.f);
        rP[q] = sp(0.f); rM[q] = sp(0.f);
    }
    v2 loc = sp(0.f);
    float4 s0m, s0e, s1m, s1e;                 // parity stage regs

    // ---- bootstrap: slots 0,1 <- rows gr(0),gr(1); stage rows gr(2),gr(3) --
    GLDP(s0m, s0e, r0 - 5);  SWR(0, s0m, s0e);
    GLDP(s1m, s1e, r0 - 4);  SWR(1, s1m, s1e);
    GLDP(s0m, s0e, r0 - 3);
    GLDP(s1m, s1e, r0 - 2);
    __builtin_amdgcn_sched_barrier(0);

    // ---- 48 steps as 4 x 12-step body; everything literal per step --------
    // step t: read row gr=r0-5+t from slot t%12, VOUT output r0+t-11 (t>=11),
    // H-push, write row gr+2 (loaded 2 steps ago) to slot (t+2)%12,
    // issue load of row gr+4 into the same parity regs.
    for (int it = 0; it < 4; ++it) {
#pragma unroll
        for (int p = 0; p < 12; ++p) {
            const int t = 12 * it + p;
            const int gr = r0 - 5 + t;
            // -- window reads from slot p (14 x ds_read_b64, literal offsets)
            v2 a[7], b[7];
#pragma unroll
            for (int k = 0; k < 7; ++k) {
                a[k] = *(const v2*)(rdp + p * SEG + 2 * k);
                b[k] = *(const v2*)(rdp + p * SEG + 144 + 2 * k);
            }
            // -- V-output from ring slots (p+1..p+11)%12 (ring-only math)
            {
                v2 S = sp(0.f), D = sp(0.f), P = sp(0.f), M = sp(0.f);
#pragma unroll
                for (int k = 0; k < 11; ++k) {
                    const int q = (p + 1 + k) % 12;
                    const v2 wk = sp(W.w[k]);
                    S = f2(wk, rS[q], S);
                    D = f2(wk, rD[q], D);
                    P = f2(wk, rP[q], P);
                    M = f2(wk, rM[q], M);
                }
                const v2 ss = S * S, dd = D * D;
                const v2 mu12  = (ss - dd) * sp(0.25f);
                const v2 musq  = (ss + dd) * sp(0.5f);
                const v2 sig12 = (P - M) * sp(0.25f) - mu12;
                const v2 sigsm = (P + M) * sp(0.5f) - musq;
                const v2 num = (sp(2.f) * mu12 + sp(C1f)) *
                               (sp(2.f) * sig12 + sp(C2f));
                const v2 den = (musq + sp(C1f)) * (sigsm + sp(C2f));
                v2 r;
                r.x = __builtin_amdgcn_rcpf(den.x);
                r.y = __builtin_amdgcn_rcpf(den.y);
                r = r * (sp(2.f) - den * r);   // one NR step
                const float vm =
                    (t >= 11 && (r0 + t - 11) < 512) ? 1.f : 0.f;
                loc = f2(num * sp(vm), r, loc);
            }
            // -- H-push row gr into ring slot p (consumes a,b)
            {
                v2 hS = sp(0.f), hD = sp(0.f), hP = sp(0.f), hM = sp(0.f);
#pragma unroll
                for (int j = 0; j < 12; ++j) {
                    const int e = j + 1;       // element col = c - 6 + e
                    const float xa = (e & 1) ? a[e >> 1].y : a[e >> 1].x;
                    const float xb = (e & 1) ? b[e >> 1].y : b[e >> 1].x;
                    const float u = xa + xb, v = xa - xb;
                    hS = f2(hpl[j], sp(u), hS);
                    hD = f2(hpl[j], sp(v), hD);
                    hP = f2(hpl[j], sp(u * u), hP);
                    hM = f2(hpl[j], sp(v * v), hM);
                }
                const float m = ((unsigned)gr < 512u) ? 1.f : 0.f;
                const v2 mm = sp(m);
                rS[p] = hS * mm; rD[p] = hD * mm;
                rP[p] = hP * mm; rM[p] = hM * mm;
            }
            // -- stage: write row gr+2 (parity regs), then load row gr+4
            if (p & 1) {
                SWR((p + 2) % 12, s1m, s1e);
                GLDP(s1m, s1e, gr + 4);
            } else {
                SWR((p + 2) % 12, s0m, s0e);
                GLDP(s0m, s0e, gr + 4);
            }
            __builtin_amdgcn_sched_barrier(0); // fence: bounds live ranges
        }
    }

    // ---- per-wave reduction -> fixed-point global atomic ----
    float l = loc.x + loc.y;
#pragma unroll
    for (int o2 = 32; o2; o2 >>= 1)
        l += __shfl_down(l, o2, 64);
    if (lane == 0) {
        const unsigned long long q =
            (unsigned long long)__double2ll_rn((double)l * SCALE);
        atomicAdd(acc, q);
    }
}

__global__ void ssim_final(const unsigned long long* __restrict__ acc,
                           float* __restrict__ out)
{
    if (threadIdx.x == 0)
        out[0] = (float)((double)(*acc) * (1.0 / SCALE) / NPIX);
}

extern "C" void kernel_launch(void* const* d_in, const int* in_sizes, int n_in,
                              void* d_out, int out_size, void* d_ws, size_t ws_size,
                              hipStream_t stream) {
    const float* img1 = (const float*)d_in[0];
    const float* img2 = (const float*)d_in[1];
    float* out = (float*)d_out;
    unsigned long long* acc = (unsigned long long*)d_ws;

    double g[11], ssum = 0.0;
    for (int i = 0; i < 11; ++i) {
        const double d = (double)(i - 5);
        g[i] = exp(-(d * d) / 4.5);
        ssum += g[i];
    }
    Wts W;
    for (int i = 0; i < 11; ++i) W.w[i] = (float)(g[i] / ssum);
    for (int j = 0; j < 12; ++j) {
        v2 p;
        p.x = (j <= 10) ? W.w[j] : 0.f;      // out0 weight for window col c-5+j
        p.y = (j >= 1) ? W.w[j - 1] : 0.f;   // out1 weight
        W.hp[j] = p;
    }

    hipMemsetAsync(d_ws, 0, sizeof(unsigned long long), stream);
    ssim_main<<<dim3(56, 48), 64, 0, stream>>>(img1, img2, acc, W);
    ssim_final<<<1, 64, 0, stream>>>(acc, out);
}

// Round 16
// 70.061 us; speedup vs baseline: 5.6483x; 5.6483x over previous
//
#include <hip/hip_runtime.h>
#include <math.h>

typedef float v2 __attribute__((ext_vector_type(2)));

#define SCALE 1073741824.0   // 2^30 fixed-point for deterministic atomic sum
#define NPIX 12582912.0      // 16*3*512*512
#define C1f 1e-4f
#define C2f 9e-4f

struct Wts {
    float w[11];   // V-pass weights
    v2 hp[12];     // H-pass pair weights for element j: (w[j]|0, w[j-1]|0)
};

__device__ __forceinline__ v2 sp(float x) { v2 r; r.x = x; r.y = x; return r; }
__device__ __forceinline__ v2 f2(v2 a, v2 b, v2 c) {
    return __builtin_elementwise_fma(a, b, c);
}

__global__ __launch_bounds__(256, 2) void ssim_main(
    const float* __restrict__ img1, const float* __restrict__ img2,
    unsigned long long* __restrict__ acc, Wts W)
{
    __shared__ float red[4];
    const int tid = threadIdx.x;
    const int lane = tid & 63;
    const int wv = tid >> 6;
    const int r0 = blockIdx.x * 33;            // 16 strips of 33 output rows
    const int plane = blockIdx.y;              // 48 planes
    const int c = wv * 128 + 2 * lane;         // this thread's columns c, c+1

    const float* baseA = img1 + (size_t)plane * 262144;
    const float* baseB = img2 + (size_t)plane * 262144;

    // per-lane clamped chunk offsets (7 x float2 chunks covering [c-6, c+8))
    int off[7];
#pragma unroll
    for (int k = 0; k < 7; ++k) {
        int o = c - 6 + 2 * k;
        off[k] = o < 0 ? 0 : (o > 510 ? 510 : o);
    }
    // per-lane H weight pairs, zeroed where the element column is out of image
    v2 hpl[12];
#pragma unroll
    for (int j = 0; j < 12; ++j) {
        const int col = c - 5 + j;
        hpl[j] = (col >= 0 && col < 512) ? W.hp[j] : sp(0.f);
    }

    v2 rS[11], rD[11], rP[11], rM[11];         // ring: blurred u, v, u^2, v^2
#pragma unroll
    for (int q = 0; q < 11; ++q) {             // zero ring: prologue VOUTs stay
        rS[q] = sp(0.f); rD[q] = sp(0.f);      // finite (den=C1*C2>0), masked
        rP[q] = sp(0.f); rM[q] = sp(0.f);
    }
    v2 a[7], b[7];
    v2 loc = sp(0.f);

    // ---- 44 steps as 4 x one 11-step body (I$-resident, R12 skeleton) ----
    // step t=11*it+p: load source row gr=r0-5+t, VOUT output row r0+t-11
    // (masked vm: t>=11 && row<512), push H-blur of row gr (masked m).
    for (int it = 0; it < 4; ++it) {
        const int t0 = 11 * it;
#pragma unroll
        for (int p = 0; p < 11; ++p) {
            const int t = t0 + p;
            const int gr = r0 - 5 + t;
            const int rc = gr < 0 ? 0 : (gr > 511 ? 511 : gr);   // uniform SALU
            const float* ra = baseA + rc * 512;  // uniform saddr base
            const float* rb = baseB + rc * 512;
#pragma unroll
            for (int k = 0; k < 7; ++k) {      // saddr + invariant voffset
                a[k] = *(const v2*)(ra + off[k]);
                b[k] = *(const v2*)(rb + off[k]);
            }
            // V-output (ring-only; overlaps the in-flight loads)
            {
                v2 S = sp(0.f), D = sp(0.f), P = sp(0.f), M = sp(0.f);
#pragma unroll
                for (int k = 0; k < 11; ++k) {
                    const int q = (p + k) % 11; // constant after unroll
                    const v2 wk = sp(W.w[k]);
                    S = f2(wk, rS[q], S);
                    D = f2(wk, rD[q], D);
                    P = f2(wk, rP[q], P);
                    M = f2(wk, rM[q], M);
                }
                const v2 ss = S * S, dd = D * D;
                const v2 mu12  = (ss - dd) * sp(0.25f);
                const v2 musq  = (ss + dd) * sp(0.5f);
                const v2 sig12 = (P - M) * sp(0.25f) - mu12;
                const v2 sigsm = (P + M) * sp(0.5f) - musq;
                const v2 num = (sp(2.f) * mu12 + sp(C1f)) *
                               (sp(2.f) * sig12 + sp(C2f));
                const v2 den = (musq + sp(C1f)) * (sigsm + sp(C2f));
                v2 r;
                r.x = __builtin_amdgcn_rcpf(den.x);
                r.y = __builtin_amdgcn_rcpf(den.y);
                r = r * (sp(2.f) - den * r);   // one NR step
                const float vm =
                    (t >= 11 && (r0 + t - 11) < 512) ? 1.f : 0.f;
                loc = f2(num * sp(vm), r, loc);
            }
            // H-push row gr into ring slot p
            {
                v2 hS = sp(0.f), hD = sp(0.f), hP = sp(0.f), hM = sp(0.f);
#pragma unroll
                for (int j = 0; j < 12; ++j) {
                    const int e = j + 1;       // element col = c - 6 + e
                    const float xa = (e & 1) ? a[e >> 1].y : a[e >> 1].x;
                    const float xb = (e & 1) ? b[e >> 1].y : b[e >> 1].x;
                    const float u = xa + xb, v = xa - xb;
                    hS = f2(hpl[j], sp(u), hS);
                    hD = f2(hpl[j], sp(v), hD);
                    hP = f2(hpl[j], sp(u * u), hP);
                    hM = f2(hpl[j], sp(v * v), hM);
                }
                const float m = ((unsigned)gr < 512u) ? 1.f : 0.f;
                const v2 mm = sp(m);
                rS[p] = hS * mm; rD[p] = hD * mm;
                rP[p] = hP * mm; rM[p] = hM * mm;
            }
            // fence pins VALU/live-ranges (anti-spill, proven R12) but lets
            // SALU(0x4) + VMEM_READ(0x20) cross -> next row's loads hoist up
            __builtin_amdgcn_sched_barrier(0x24);
        }
    }

    // ---- reduction -> fixed-point global atomic ----
    float l = loc.x + loc.y;
#pragma unroll
    for (int o2 = 32; o2; o2 >>= 1)
        l += __shfl_down(l, o2, 64);
    if (lane == 0) red[wv] = l;
    __syncthreads();
    if (tid == 0) {
        const float bs = red[0] + red[1] + red[2] + red[3];
        const unsigned long long q =
            (unsigned long long)__double2ll_rn((double)bs * SCALE);
        atomicAdd(acc, q);
    }
}

__global__ void ssim_final(const unsigned long long* __restrict__ acc,
                           float* __restrict__ out)
{
    if (threadIdx.x == 0)
        out[0] = (float)((double)(*acc) * (1.0 / SCALE) / NPIX);
}

extern "C" void kernel_launch(void* const* d_in, const int* in_sizes, int n_in,
                              void* d_out, int out_size, void* d_ws, size_t ws_size,
                              hipStream_t stream) {
    const float* img1 = (const float*)d_in[0];
    const float* img2 = (const float*)d_in[1];
    float* out = (float*)d_out;
    unsigned long long* acc = (unsigned long long*)d_ws;

    double g[11], ssum = 0.0;
    for (int i = 0; i < 11; ++i) {
        const double d = (double)(i - 5);
        g[i] = exp(-(d * d) / 4.5);
        ssum += g[i];
    }
    Wts W;
    for (int i = 0; i < 11; ++i) W.w[i] = (float)(g[i] / ssum);
    for (int j = 0; j < 12; ++j) {
        v2 p;
        p.x = (j <= 10) ? W.w[j] : 0.f;      // out0 weight for window col c-5+j
        p.y = (j >= 1) ? W.w[j - 1] : 0.f;   // out1 weight
        W.hp[j] = p;
    }

    hipMemsetAsync(d_ws, 0, sizeof(unsigned long long), stream);
    ssim_main<<<dim3(16, 48), 256, 0, stream>>>(img1, img2, acc, W);
    ssim_final<<<1, 64, 0, stream>>>(acc, out);
}